// Round 12
// baseline (7368.162 us; speedup 1.0000x reference)
//
#include <hip/hip_runtime.h>
#include <hip/hip_bf16.h>
#include <math.h>

typedef __hip_bfloat16 bf16;
typedef __attribute__((ext_vector_type(8))) short s8v;   // 8 x bf16 bits
typedef __attribute__((ext_vector_type(4))) short s4v;   // 4 x bf16 bits
typedef __attribute__((ext_vector_type(4))) float f4v;   // MFMA accumulator

static __device__ __forceinline__ float bfs2f(short s) {
    return __uint_as_float(((unsigned)(unsigned short)s) << 16);
}
static __device__ __forceinline__ short f2bfs(float f) {
    __hip_bfloat16 h = __float2bfloat16(f);
    return *reinterpret_cast<short*>(&h);
}

// ---------------------------------------------------------------------------
// fp32 -> bf16 conversion (vectorized x4).
// ---------------------------------------------------------------------------
__global__ __launch_bounds__(256)
void cvt_f32_bf16(const float* __restrict__ in, bf16* __restrict__ out, long n4)
{
    const long i = (long)blockIdx.x * 256 + threadIdx.x;
    if (i >= n4) return;
    const float4 v = reinterpret_cast<const float4*>(in)[i];
    s4v o;
    o[0] = f2bfs(v.x); o[1] = f2bfs(v.y); o[2] = f2bfs(v.z); o[3] = f2bfs(v.w);
    reinterpret_cast<s4v*>(out)[i] = o;
}

// ---------------------------------------------------------------------------
// fp32 [R x C] -> bf16 transposed [C x R], 32x32 LDS tiles.
// ---------------------------------------------------------------------------
__global__ __launch_bounds__(256)
void cvt_t_f32_bf16(const float* __restrict__ in, bf16* __restrict__ out,
                    int R, int C)
{
    __shared__ float t[32][33];
    const int bx = blockIdx.x * 32;
    const int by = blockIdx.y * 32;
    const int tx = threadIdx.x & 31;
    const int ty = threadIdx.x >> 5;
#pragma unroll
    for (int r = ty; r < 32; r += 8)
        t[r][tx] = in[(long)(by + r) * C + bx + tx];
    __syncthreads();
#pragma unroll
    for (int r = ty; r < 32; r += 8)
        out[(long)(bx + r) * R + by + tx] = __float2bfloat16(t[tx][r]);
}

// ---------------------------------------------------------------------------
// b1p[m] = b1[m] + sum_br sum_k w1[m, br*512+k] * bo_br[k]   (fp32)
// ---------------------------------------------------------------------------
__global__ __launch_bounds__(256)
void fold_b1(const float* __restrict__ w1, const float* __restrict__ bo0,
             const float* __restrict__ bo1, const float* __restrict__ bo2,
             const float* __restrict__ b1, float* __restrict__ b1p)
{
    const int m = blockIdx.x * 256 + threadIdx.x;
    float s = b1[m];
    const float* w = w1 + (long)m * 1536;
    for (int k = 0; k < 512; ++k) s += w[k]        * bo0[k];
    for (int k = 0; k < 512; ++k) s += w[512 + k]  * bo1[k];
    for (int k = 0; k < 512; ++k) s += w[1024 + k] * bo2[k];
    b1p[m] = s;
}

// ---------------------------------------------------------------------------
// 256x256 GEMM: C[M,N](bf16) = act(A[M,K] @ B[N,K]^T + bias[N])
// SINGLE-buffered LDS (64 KiB) -> 2 blocks/CU; per K-tile:
//   vmcnt(0)+barrier -> [8 B-reads + 4x(4 A-reads + 16 MFMA)] -> barrier
//   -> stage(t+1).
// Intra-block stage->use stall is covered by the CO-RESIDENT block's compute
// (TLP, not ILP — R6/R8/R10 falsified 1-block ILP variants). XOR bank-swizzle
// (chunk ^= row&7 both sides, rule #21), setprio (T5), bijective XCD swizzle
// (m204), LDS-staged coalesced epilogue in 2 passes (8 KiB/wave live).
// Requires M%256==0, N%256==0, K%64==0.
// Grid (N/256, M/256). A stride lda, B is [N,K]. bias fp32 (coff-indexed) or null.
// ---------------------------------------------------------------------------
template<int ACT>
__global__ __launch_bounds__(512, 4)
void gemm256(const bf16* __restrict__ A, const bf16* __restrict__ B,
             const float* __restrict__ bias, bf16* __restrict__ C,
             int K, int lda, int ldc, int coff)
{
    __shared__ __align__(16) bf16 sA[256 * 64];   // 32 KiB
    __shared__ __align__(16) bf16 sB[256 * 64];   // 32 KiB
    const int tid  = threadIdx.x;
    const int lane = tid & 63;
    const int wid  = tid >> 6;             // 0..7
    // bijective XCD-chunked swizzle (works for any nwg)
    const int nwg  = gridDim.x * gridDim.y;
    const int orig = blockIdx.x + gridDim.x * blockIdx.y;
    const int q = nwg >> 3, r = nwg & 7, xcd = orig & 7;
    const int sb = (xcd < r ? xcd * (q + 1) : r * (q + 1) + (xcd - r) * q) + (orig >> 3);
    const int bCol = sb % gridDim.x;
    const int bRow = sb / gridDim.x;

    const int wr  = (wid >> 2) * 128;      // wave M offset in tile
    const int wc  = (wid & 3) * 64;        // wave N offset in tile
    const int fr  = lane & 15;
    const int hi4 = lane >> 4;             // 0..3
    const int rx  = fr & 7;                // row&7 for fragment-read swizzle

    f4v acc[8][4];
#pragma unroll
    for (int i = 0; i < 8; ++i)
#pragma unroll
        for (int j = 0; j < 4; ++j) acc[i][j] = (f4v)(0.0f);

    // staging geometry: thread t stages (row = h*128 + l*64 + t/8, chunk = t&7);
    // linear LDS dest h*16384 + l*8192 + t*16; source column pre-swizzled.
    const int srow = tid >> 3;                           // 0..63
    const int scol = ((tid & 7) ^ (srow & 7)) * 8;       // source elem offset
    const bf16* Abase = A + (long)(bRow * 256 + srow) * lda + scol;
    const bf16* Bbase = B + (long)(bCol * 256 + srow) * K + scol;

#define GL16(src, dst)                                                          \
    __builtin_amdgcn_global_load_lds(                                           \
        (const __attribute__((address_space(1))) unsigned int*)(src),           \
        (__attribute__((address_space(3))) unsigned int*)(dst), 16, 0, 0)

#define STAGE_A(h, tt) do {                                                     \
    const bf16* g_ = Abase + (long)(h) * 128 * lda + (long)(tt) * 64;           \
    char* d_ = (char*)sA + (h) * 16384 + tid * 16;                              \
    GL16(g_, d_); GL16(g_ + 64 * (long)lda, d_ + 8192); } while (0)

#define STAGE_B(h, tt) do {                                                     \
    const bf16* g_ = Bbase + (long)(h) * 128 * K + (long)(tt) * 64;             \
    char* d_ = (char*)sB + (h) * 16384 + tid * 16;                              \
    GL16(g_, d_); GL16(g_ + 64 * (long)K, d_ + 8192); } while (0)

#define LDSW(base, row, kk)                                                     \
    (*(const s8v*)((base) + (row) * 128 + ((((kk) * 4 + hi4) ^ rx) << 4)))

    const int nk = K >> 6;

    // stage tile 0
    STAGE_A(0, 0); STAGE_A(1, 0); STAGE_B(0, 0); STAGE_B(1, 0);

    for (int t = 0; t < nk; ++t) {
        asm volatile("s_waitcnt vmcnt(0)" ::: "memory");  // tile t landed
        __builtin_amdgcn_s_barrier();
        __builtin_amdgcn_sched_barrier(0);

        const char* sAc = (const char*)sA;
        const char* sBc = (const char*)sB;
        // B fragments for the whole tile
        s8v bfr[4][2];
#pragma unroll
        for (int ni = 0; ni < 4; ++ni)
#pragma unroll
            for (int kk = 0; kk < 2; ++kk)
                bfr[ni][kk] = LDSW(sBc, wc + ni * 16 + fr, kk);

        // 4 groups of (4 A-frag reads + 16 MFMA); compiler pipelines via lgkmcnt
#pragma unroll
        for (int g = 0; g < 4; ++g) {
            s8v a0[2], a1[2];
#pragma unroll
            for (int kk = 0; kk < 2; ++kk) {
                a0[kk] = LDSW(sAc, wr + (2 * g) * 16 + fr, kk);
                a1[kk] = LDSW(sAc, wr + (2 * g + 1) * 16 + fr, kk);
            }
            __builtin_amdgcn_s_setprio(1);
#pragma unroll
            for (int kk = 0; kk < 2; ++kk)
#pragma unroll
                for (int ni = 0; ni < 4; ++ni) {
                    acc[2 * g][ni] = __builtin_amdgcn_mfma_f32_16x16x32_bf16(
                        a0[kk], bfr[ni][kk], acc[2 * g][ni], 0, 0, 0);
                    acc[2 * g + 1][ni] = __builtin_amdgcn_mfma_f32_16x16x32_bf16(
                        a1[kk], bfr[ni][kk], acc[2 * g + 1][ni], 0, 0, 0);
                }
            __builtin_amdgcn_s_setprio(0);
        }

        __builtin_amdgcn_s_barrier();      // all waves done reading tile t
        __builtin_amdgcn_sched_barrier(0);
        if (t + 1 < nk) {
            STAGE_A(0, t + 1); STAGE_A(1, t + 1);
            STAGE_B(0, t + 1); STAGE_B(1, t + 1);
        }
    }
#undef STAGE_A
#undef STAGE_B
#undef GL16
#undef LDSW

    // -------- LDS-staged coalesced epilogue, 2 passes (8 KiB/wave) --------
    __syncthreads();   // all waves done with K-loop LDS
    bf16* ep = (wid < 4) ? (sA + wid * 4096) : (sB + (wid - 4) * 4096);  // [64][64]
    const int frow = hi4 * 4;
    const long rowBase = (long)bRow * 256 + wr;
    const int  colBase = bCol * 256 + wc;
    const int lr8 = lane >> 3;          // 0..7 row-in-round
    const int lc  = (lane & 7) * 8;     // col element offset
#pragma unroll
    for (int half = 0; half < 2; ++half) {
#pragma unroll
        for (int ni = 0; ni < 4; ++ni) {
            const int col = colBase + ni * 16 + fr;
            const float bi = bias ? bias[coff + col] : 0.0f;
#pragma unroll
            for (int mi = 0; mi < 4; ++mi) {
#pragma unroll
                for (int j = 0; j < 4; ++j) {
                    float v = acc[half * 4 + mi][ni][j] + bi;
                    if (ACT == 1) {  // gelu, tanh approx (max abs err ~7e-4)
                        const float u = v * (0.7978845608f + 0.0356774081f * v * v);
                        const float tnh = 1.0f - 2.0f / (__expf(2.0f * u) + 1.0f);
                        v = 0.5f * v * (1.0f + tnh);
                    }
                    ep[(mi * 16 + frow + j) * 64 + ni * 16 + fr] = __float2bfloat16(v);
                }
            }
        }
        asm volatile("s_waitcnt lgkmcnt(0)" ::: "memory");
        __builtin_amdgcn_sched_barrier(0);
        // stream out: 8 rounds x 8 rows, 16B/lane fully-coalesced
#pragma unroll
        for (int q2 = 0; q2 < 8; ++q2) {
            const int lrow = q2 * 8 + lr8;
            const s8v vv = *(const s8v*)(&ep[lrow * 64 + lc]);
            *(s8v*)(&C[(rowBase + half * 64 + lrow) * (long)ldc + coff + colBase + lc]) = vv;
        }
        asm volatile("s_waitcnt lgkmcnt(0)" ::: "memory");  // reads done before pass-2 writes
        __builtin_amdgcn_sched_barrier(0);
    }
}

// ---------------------------------------------------------------------------
// Barrier-free attention over 9-token sequences (R9, measured BW-bound-good).
// ---------------------------------------------------------------------------
__device__ __forceinline__ int cell9(int branch, int g, int p)
{
    if (branch == 0) return g * 9 + p;
    if (branch == 1) return p * 9 + g;
    return ((g / 3) * 3 + p / 3) * 9 + (g % 3) * 3 + (p % 3);
}

__global__ __launch_bounds__(256)
void attn9(const bf16* __restrict__ qkv, bf16* __restrict__ outg,
           long chunk_base)
{
    __shared__ __align__(16) bf16 sW[4 * 9 * 392];
    __shared__ float sP[4][2][84];
    const int tid  = threadIdx.x;
    const int lane = tid & 63;
    const int w    = tid >> 6;
    const int branch = blockIdx.y;
    const int bx = blockIdx.x;
    const int s = (bx & 7) * (2304 >> 3) + (bx >> 3);
    const int b = s / 9, g = s % 9;
    const long brOff = (long)branch * 1536;
    bf16* myW = sW + w * (9 * 392);

#pragma unroll
    for (int rr = 0; rr < 7; ++rr) {
        const int c = rr * 64 + lane;
        if (c < 432) {
            const int p   = c / 48;
            const int rem = c - p * 48;
            const int seg = rem >> 3;
            const int ch  = rem & 7;
            const int col = (seg >> 1) * 512 + ((w << 1) + (seg & 1)) * 64 + ch * 8;
            const long tok = b * 81 + cell9(branch, g, p);
            *(s8v*)(&myW[p * 392 + seg * 64 + ch * 8]) =
                *(const s8v*)(&qkv[tok * 4608 + brOff + col]);
        }
    }
    asm volatile("s_waitcnt lgkmcnt(0) vmcnt(0)" ::: "memory");
    __builtin_amdgcn_sched_barrier(0);

#pragma unroll
    for (int rr = 0; rr < 3; ++rr) {
        const int idx = rr * 64 + lane;
        if (idx < 162) {
            const int h2 = idx / 81;
            const int pr = idx - h2 * 81;
            const int i = pr / 9, j = pr - (pr / 9) * 9;
            const bf16* qp = &myW[i * 392 + h2 * 64];
            const bf16* kp = &myW[j * 392 + 128 + h2 * 64];
            float accd = 0.0f;
#pragma unroll
            for (int dc = 0; dc < 8; ++dc) {
                s8v qv = *(const s8v*)(qp + dc * 8);
                s8v kv = *(const s8v*)(kp + dc * 8);
#pragma unroll
                for (int e2 = 0; e2 < 8; ++e2)
                    accd += bfs2f(qv[e2]) * bfs2f(kv[e2]);
            }
            sP[w][h2][pr] = accd * 0.125f;
        }
    }
    asm volatile("s_waitcnt lgkmcnt(0)" ::: "memory");
    __builtin_amdgcn_sched_barrier(0);

    if (lane < 18) {
        const int h2 = lane / 9, i = lane - (lane / 9) * 9;
        float* row = &sP[w][h2][i * 9];
        float m = row[0];
#pragma unroll
        for (int j = 1; j < 9; ++j) m = fmaxf(m, row[j]);
        float sum = 0.f, e[9];
#pragma unroll
        for (int j = 0; j < 9; ++j) { e[j] = expf(row[j] - m); sum += e[j]; }
        const float inv = 1.0f / sum;
#pragma unroll
        for (int j = 0; j < 9; ++j) row[j] = e[j] * inv;
    }
    asm volatile("s_waitcnt lgkmcnt(0)" ::: "memory");
    __builtin_amdgcn_sched_barrier(0);

#pragma unroll
    for (int rr = 0; rr < 3; ++rr) {
        const int idx = rr * 64 + lane;
        if (idx < 144) {
            const int h2  = idx / 72;
            const int rem = idx - h2 * 72;
            const int i  = rem >> 3;
            const int c8 = (rem & 7) * 8;
            const float* prow = &sP[w][h2][i * 9];
            float accv[8];
#pragma unroll
            for (int q2 = 0; q2 < 8; ++q2) accv[q2] = 0.f;
#pragma unroll
            for (int j = 0; j < 9; ++j) {
                const float p = prow[j];
                const s8v vv = *(const s8v*)(&myW[j * 392 + 256 + h2 * 64 + c8]);
#pragma unroll
                for (int q2 = 0; q2 < 8; ++q2)
                    accv[q2] += p * bfs2f(vv[q2]);
            }
            s8v ov;
#pragma unroll
            for (int q2 = 0; q2 < 8; ++q2) ov[q2] = f2bfs(accv[q2]);
            const long tok = b * 81 + cell9(branch, g, i);
            const int ocol = ((w << 1) + h2) * 64 + c8;
            *(s8v*)(&outg[(chunk_base + tok) * 1536 + branch * 512 + ocol]) = ov;
        }
    }
}

// ---------------------------------------------------------------------------
// Residual + LayerNorm: out = LN(x + mixed) * gamma + beta, E=512. fp32 I/O.
// ---------------------------------------------------------------------------
__global__ __launch_bounds__(256)
void ln_res(const float* __restrict__ x, const bf16* __restrict__ mixed,
            const float* __restrict__ gamma, const float* __restrict__ beta,
            float* __restrict__ out)
{
    const int tid = threadIdx.x;
    const int lane = tid & 63;
    const long row = (long)blockIdx.x * 4 + (tid >> 6);
    const long base = row * 512 + lane * 8;
    const float4 x0 = *(const float4*)(&x[base]);
    const float4 x1 = *(const float4*)(&x[base + 4]);
    const s8v mv = *(const s8v*)(&mixed[base]);
    float y[8];
    y[0] = x0.x + bfs2f(mv[0]); y[1] = x0.y + bfs2f(mv[1]);
    y[2] = x0.z + bfs2f(mv[2]); y[3] = x0.w + bfs2f(mv[3]);
    y[4] = x1.x + bfs2f(mv[4]); y[5] = x1.y + bfs2f(mv[5]);
    y[6] = x1.z + bfs2f(mv[6]); y[7] = x1.w + bfs2f(mv[7]);
    float sum = 0.f, sq = 0.f;
#pragma unroll
    for (int j = 0; j < 8; ++j) { sum += y[j]; sq += y[j] * y[j]; }
#pragma unroll
    for (int o = 32; o > 0; o >>= 1) {
        sum += __shfl_xor(sum, o, 64);
        sq  += __shfl_xor(sq, o, 64);
    }
    const float mean = sum * (1.f / 512.f);
    const float inv = rsqrtf(sq * (1.f / 512.f) - mean * mean + 1e-5f);
    const float4 g0 = *(const float4*)(&gamma[lane * 8]);
    const float4 g1 = *(const float4*)(&gamma[lane * 8 + 4]);
    const float4 b0 = *(const float4*)(&beta[lane * 8]);
    const float4 b1 = *(const float4*)(&beta[lane * 8 + 4]);
    float4 o0, o1;
    o0.x = (y[0] - mean) * inv * g0.x + b0.x;
    o0.y = (y[1] - mean) * inv * g0.y + b0.y;
    o0.z = (y[2] - mean) * inv * g0.z + b0.z;
    o0.w = (y[3] - mean) * inv * g0.w + b0.w;
    o1.x = (y[4] - mean) * inv * g1.x + b1.x;
    o1.y = (y[5] - mean) * inv * g1.y + b1.y;
    o1.z = (y[6] - mean) * inv * g1.z + b1.z;
    o1.w = (y[7] - mean) * inv * g1.w + b1.w;
    *(float4*)(&out[base]) = o0;
    *(float4*)(&out[base + 4]) = o1;
}

// ---------------------------------------------------------------------------
extern "C" void kernel_launch(void* const* d_in, const int* in_sizes, int n_in,
                              void* d_out, int out_size, void* d_ws, size_t ws_size,
                              hipStream_t stream)
{
    (void)in_sizes; (void)n_in; (void)out_size; (void)ws_size;
    const float* x     = (const float*)d_in[0];
    const float* w1f   = (const float*)d_in[13];
    const float* b1f   = (const float*)d_in[14];
    const float* b2f   = (const float*)d_in[16];
    const float* gamma = (const float*)d_in[17];
    const float* beta  = (const float*)d_in[18];

    // ---- workspace layout (total ~543 MB; proven-safe < 594.5 MB) ----
    char* ws = (char*)d_ws;
    bf16* attnall   = (bf16*)(ws);                    // [82944x1536]
    bf16* mixed     = (bf16*)(ws);                    // reuses attnall
    char* R         = ws + 254803968LL;
    bf16* qkv3chunk = (bf16*)(R);                     // [20736x4608]
    bf16* xb        = (bf16*)(R + 191102976LL);       // [82944x512]
    bf16* h         = (bf16*)(R);                     // [82944x1024] reuses R
    char* wb        = ws + 530841600LL;
    long off = 0;
    bf16* wqkv3_b = (bf16*)(wb + off); off += 4718592;   // [4608 x 512]
    bf16* woT_b[3];
    for (int i = 0; i < 3; ++i) { woT_b[i] = (bf16*)(wb + off); off += 524288; }
    bf16* w1_b  = (bf16*)(wb + off); off += 3145728;
    bf16* w2_b  = (bf16*)(wb + off); off += 1048576;
    bf16* Wp    = (bf16*)(wb + off); off += 3145728;
    float* b1p  = (float*)(wb + off); off += 4096;
    float* bqkv3 = (float*)(wb + off); off += 18432;     // [4608] fp32

    const dim3 blk(256, 1, 1);
    const dim3 blk512(512, 1, 1);

    // conversions
    cvt_f32_bf16<<<dim3(41472), blk, 0, stream>>>(x, xb, 10616832L);
    for (int i = 0; i < 3; ++i) {
        cvt_f32_bf16<<<dim3(768), blk, 0, stream>>>(
            (const float*)d_in[1 + i * 4], wqkv3_b + (long)i * 786432, 196608L);
        cvt_t_f32_bf16<<<dim3(16, 16), blk, 0, stream>>>(
            (const float*)d_in[3 + i * 4], woT_b[i], 512, 512);
        hipMemcpyAsync(bqkv3 + i * 1536, d_in[2 + i * 4], 1536 * sizeof(float),
                       hipMemcpyDeviceToDevice, stream);
    }
    cvt_f32_bf16<<<dim3(1536), blk, 0, stream>>>(w1f, w1_b, 393216L);
    cvt_f32_bf16<<<dim3(512), blk, 0, stream>>>((const float*)d_in[15], w2_b, 131072L);

    // bias fold: b1p = b1 + sum_br w1_br @ bo_br
    fold_b1<<<dim3(4), blk, 0, stream>>>(w1f, (const float*)d_in[4],
                                         (const float*)d_in[8], (const float*)d_in[12],
                                         b1f, b1p);

    // Wp[:, br*512+k] = (w1_br @ wo_br)[:, k]   M=1024, N=512, K=512
    for (int br = 0; br < 3; ++br)
        gemm256<0><<<dim3(2, 4), blk512, 0, stream>>>(
            w1_b + br * 512, woT_b[br], nullptr, Wp, 512, 1536, 1536, br * 512);

    // attention phase: 4 chunks of 256 batches (20736 rows)
    const long ROWS_C = 20736;
    for (int c = 0; c < 4; ++c) {
        const bf16* xA = xb + c * ROWS_C * 512;
        // qkv3 = x_chunk @ wqkv3^T + bqkv3   [20736, 4608]
        gemm256<0><<<dim3(18, 81), blk512, 0, stream>>>(
            xA, wqkv3_b, bqkv3, qkv3chunk, 512, 512, 4608, 0);
        // attention, all 3 branches -> attnall
        attn9<<<dim3(2304, 3), blk, 0, stream>>>(qkv3chunk, attnall, c * ROWS_C);
    }
    // h = gelu(attnall @ Wp^T + b1p)  [82944, 1024]
    gemm256<1><<<dim3(4, 324), blk512, 0, stream>>>(attnall, Wp, b1p, h, 1536, 1536, 1024, 0);
    // mixed = h @ w2^T + b2  [82944, 512]
    gemm256<0><<<dim3(2, 324), blk512, 0, stream>>>(h, w2_b, b2f, mixed, 1024, 1024, 512, 0);
    // out = LayerNorm(x + mixed), fp32
    ln_res<<<dim3(20736), blk, 0, stream>>>(x, mixed, gamma, beta, (float*)d_out);
}

// Round 13
// 1423.222 us; speedup vs baseline: 5.1771x; 5.1771x over previous
//
#include <hip/hip_runtime.h>
#include <hip/hip_bf16.h>
#include <math.h>

typedef __hip_bfloat16 bf16;
typedef __attribute__((ext_vector_type(8))) short s8v;   // 8 x bf16 bits
typedef __attribute__((ext_vector_type(4))) short s4v;   // 4 x bf16 bits
typedef __attribute__((ext_vector_type(4))) float f4v;   // MFMA accumulator

static __device__ __forceinline__ float bfs2f(short s) {
    return __uint_as_float(((unsigned)(unsigned short)s) << 16);
}
static __device__ __forceinline__ short f2bfs(float f) {
    __hip_bfloat16 h = __float2bfloat16(f);
    return *reinterpret_cast<short*>(&h);
}

// ---------------------------------------------------------------------------
// fp32 -> bf16 conversion (vectorized x4).
// ---------------------------------------------------------------------------
__global__ __launch_bounds__(256)
void cvt_f32_bf16(const float* __restrict__ in, bf16* __restrict__ out, long n4)
{
    const long i = (long)blockIdx.x * 256 + threadIdx.x;
    if (i >= n4) return;
    const float4 v = reinterpret_cast<const float4*>(in)[i];
    s4v o;
    o[0] = f2bfs(v.x); o[1] = f2bfs(v.y); o[2] = f2bfs(v.z); o[3] = f2bfs(v.w);
    reinterpret_cast<s4v*>(out)[i] = o;
}

// ---------------------------------------------------------------------------
// fp32 [R x C] -> bf16 transposed [C x R], 32x32 LDS tiles.
// ---------------------------------------------------------------------------
__global__ __launch_bounds__(256)
void cvt_t_f32_bf16(const float* __restrict__ in, bf16* __restrict__ out,
                    int R, int C)
{
    __shared__ float t[32][33];
    const int bx = blockIdx.x * 32;
    const int by = blockIdx.y * 32;
    const int tx = threadIdx.x & 31;
    const int ty = threadIdx.x >> 5;
#pragma unroll
    for (int r = ty; r < 32; r += 8)
        t[r][tx] = in[(long)(by + r) * C + bx + tx];
    __syncthreads();
#pragma unroll
    for (int r = ty; r < 32; r += 8)
        out[(long)(bx + r) * R + by + tx] = __float2bfloat16(t[tx][r]);
}

// ---------------------------------------------------------------------------
// b1p[m] = b1[m] + sum_br sum_k w1[m, br*512+k] * bo_br[k]   (fp32)
// ---------------------------------------------------------------------------
__global__ __launch_bounds__(256)
void fold_b1(const float* __restrict__ w1, const float* __restrict__ bo0,
             const float* __restrict__ bo1, const float* __restrict__ bo2,
             const float* __restrict__ b1, float* __restrict__ b1p)
{
    const int m = blockIdx.x * 256 + threadIdx.x;
    float s = b1[m];
    const float* w = w1 + (long)m * 1536;
    for (int k = 0; k < 512; ++k) s += w[k]        * bo0[k];
    for (int k = 0; k < 512; ++k) s += w[512 + k]  * bo1[k];
    for (int k = 0; k < 512; ++k) s += w[1024 + k] * bo2[k];
    b1p[m] = s;
}

// ---------------------------------------------------------------------------
// 256x256 GEMM: C[M,N](bf16) = act(A[M,K] @ B[N,K]^T + bias[N])
// K-loop = R7/R9 measured-best schedule: 8 waves (2M x 4N), BK=64, double-
// buffered LDS, XOR bank-swizzle (chunk ^= row&7 both sides, rule #21),
// TWO barriers per K-tile (mid barrier paces wave convoys + guards B-stage),
// counted vmcnt(4) at tile boundary (loads in flight across barriers, T4),
// setprio (T5), bijective XCD swizzle (m204). Epilogue = LDS-staged
// coalesced stores (WRITE_SIZE = ideal) + XOR col-block swizzle
// (col ^= ((row>>2)&3)<<4) to kill the 8-way epilogue write conflicts.
// [R8/R10 falsified: single-barrier variants regress to ~24.7% MfmaUtil;
//  R12 falsified: 2 blocks/CU impossible at 256^2 (acc=128 regs > 128 cap).]
// Requires M%256==0, N%256==0, K%64==0, K>=128.
// Grid (N/256, M/256). A stride lda, B is [N,K]. bias fp32 (coff-indexed) or null.
// ---------------------------------------------------------------------------
template<int ACT>
__global__ __launch_bounds__(512, 2)
void gemm256(const bf16* __restrict__ A, const bf16* __restrict__ B,
             const float* __restrict__ bias, bf16* __restrict__ C,
             int K, int lda, int ldc, int coff)
{
    __shared__ __align__(16) bf16 sA[2][256 * 64];   // 64 KiB
    __shared__ __align__(16) bf16 sB[2][256 * 64];   // 64 KiB
    const int tid  = threadIdx.x;
    const int lane = tid & 63;
    const int wid  = tid >> 6;             // 0..7
    // bijective XCD-chunked swizzle (works for any nwg)
    const int nwg  = gridDim.x * gridDim.y;
    const int orig = blockIdx.x + gridDim.x * blockIdx.y;
    const int q = nwg >> 3, r = nwg & 7, xcd = orig & 7;
    const int sb = (xcd < r ? xcd * (q + 1) : r * (q + 1) + (xcd - r) * q) + (orig >> 3);
    const int bCol = sb % gridDim.x;
    const int bRow = sb / gridDim.x;

    const int wr  = (wid >> 2) * 128;      // wave M offset in tile
    const int wc  = (wid & 3) * 64;        // wave N offset in tile
    const int fr  = lane & 15;
    const int hi4 = lane >> 4;             // 0..3
    const int rx  = fr & 7;                // row&7 for fragment-read swizzle

    f4v acc[8][4];
#pragma unroll
    for (int i = 0; i < 8; ++i)
#pragma unroll
        for (int j = 0; j < 4; ++j) acc[i][j] = (f4v)(0.0f);

    // staging geometry: thread t stages (row = h*128 + l*64 + t/8, chunk = t&7);
    // linear LDS dest h*16384 + l*8192 + t*16; source column pre-swizzled.
    const int srow = tid >> 3;                           // 0..63
    const int scol = ((tid & 7) ^ (srow & 7)) * 8;       // source elem offset
    const bf16* Abase = A + (long)(bRow * 256 + srow) * lda + scol;
    const bf16* Bbase = B + (long)(bCol * 256 + srow) * K + scol;

#define GL16(src, dst)                                                          \
    __builtin_amdgcn_global_load_lds(                                           \
        (const __attribute__((address_space(1))) unsigned int*)(src),           \
        (__attribute__((address_space(3))) unsigned int*)(dst), 16, 0, 0)

#define STAGE_A(h, tt, bc) do {                                                 \
    const bf16* g_ = Abase + (long)(h) * 128 * lda + (long)(tt) * 64;           \
    char* d_ = (char*)sA[bc] + (h) * 16384 + tid * 16;                          \
    GL16(g_, d_); GL16(g_ + 64 * (long)lda, d_ + 8192); } while (0)

#define STAGE_B(h, tt, bc) do {                                                 \
    const bf16* g_ = Bbase + (long)(h) * 128 * K + (long)(tt) * 64;             \
    char* d_ = (char*)sB[bc] + (h) * 16384 + tid * 16;                          \
    GL16(g_, d_); GL16(g_ + 64 * (long)K, d_ + 8192); } while (0)

#define LDSW(base, row, kk)                                                     \
    (*(const s8v*)((base) + (row) * 128 + ((((kk) * 4 + hi4) ^ rx) << 4)))

    const int nk = K >> 6;   // >= 2 by contract

    // prologue: tile0 (4 half-tiles) -> buf0; B of tile1 -> buf1
    STAGE_A(0, 0, 0); STAGE_A(1, 0, 0);
    STAGE_B(0, 0, 0); STAGE_B(1, 0, 0);
    STAGE_B(0, 1, 1); STAGE_B(1, 1, 1);
    asm volatile("s_waitcnt vmcnt(4)" ::: "memory");   // tile0 landed; B(1) in flight
    __builtin_amdgcn_s_barrier();
    __builtin_amdgcn_sched_barrier(0);

    for (int t = 0; t < nk; ++t) {
        const int c = t & 1;
        const char* sAc = (const char*)sA[c];
        const char* sBc = (const char*)sB[c];
        s8v bfr[4][2];

        // ---- half 1: wave-tile rows 0..63 (mi 0..3); stage A(t+1) ----
        {
            s8v af0[2][2], af1[2][2];
#pragma unroll
            for (int m2 = 0; m2 < 2; ++m2)
#pragma unroll
                for (int kk = 0; kk < 2; ++kk) {
                    af0[m2][kk] = LDSW(sAc, wr + m2 * 16 + fr, kk);
                    af1[m2][kk] = LDSW(sAc, wr + (2 + m2) * 16 + fr, kk);
                }
#pragma unroll
            for (int ni = 0; ni < 4; ++ni)
#pragma unroll
                for (int kk = 0; kk < 2; ++kk)
                    bfr[ni][kk] = LDSW(sBc, wc + ni * 16 + fr, kk);
            if (t + 1 < nk) { STAGE_A(0, t + 1, c ^ 1); STAGE_A(1, t + 1, c ^ 1); }
            __builtin_amdgcn_s_setprio(1);
#pragma unroll
            for (int kk = 0; kk < 2; ++kk)
#pragma unroll
                for (int m2 = 0; m2 < 2; ++m2)
#pragma unroll
                    for (int ni = 0; ni < 4; ++ni) {
                        acc[m2][ni] = __builtin_amdgcn_mfma_f32_16x16x32_bf16(
                            af0[m2][kk], bfr[ni][kk], acc[m2][ni], 0, 0, 0);
                        acc[2 + m2][ni] = __builtin_amdgcn_mfma_f32_16x16x32_bf16(
                            af1[m2][kk], bfr[ni][kk], acc[2 + m2][ni], 0, 0, 0);
                    }
            __builtin_amdgcn_s_setprio(0);
        }
        __builtin_amdgcn_s_barrier();   // B-reads (half1) done before STAGE_B below

        // ---- half 2: wave-tile rows 64..127 (mi 4..7); stage B(t+2) ----
        {
            s8v af0[2][2], af1[2][2];
#pragma unroll
            for (int m2 = 0; m2 < 2; ++m2)
#pragma unroll
                for (int kk = 0; kk < 2; ++kk) {
                    af0[m2][kk] = LDSW(sAc, wr + (4 + m2) * 16 + fr, kk);
                    af1[m2][kk] = LDSW(sAc, wr + (6 + m2) * 16 + fr, kk);
                }
            if (t + 2 < nk) { STAGE_B(0, t + 2, c); STAGE_B(1, t + 2, c); }
            __builtin_amdgcn_s_setprio(1);
#pragma unroll
            for (int kk = 0; kk < 2; ++kk)
#pragma unroll
                for (int m2 = 0; m2 < 2; ++m2)
#pragma unroll
                    for (int ni = 0; ni < 4; ++ni) {
                        acc[4 + m2][ni] = __builtin_amdgcn_mfma_f32_16x16x32_bf16(
                            af0[m2][kk], bfr[ni][kk], acc[4 + m2][ni], 0, 0, 0);
                        acc[6 + m2][ni] = __builtin_amdgcn_mfma_f32_16x16x32_bf16(
                            af1[m2][kk], bfr[ni][kk], acc[6 + m2][ni], 0, 0, 0);
                    }
            __builtin_amdgcn_s_setprio(0);
        }
        // tile boundary: wait own DMA (counted), THEN barrier => all waves' landed
        if (t + 2 < nk) {
            asm volatile("s_waitcnt vmcnt(4)" ::: "memory");  // B(t+1)+A(t+1) landed
        } else if (t + 1 < nk) {
            asm volatile("s_waitcnt vmcnt(0)" ::: "memory");  // final drain
        }
        __builtin_amdgcn_s_barrier();
        __builtin_amdgcn_sched_barrier(0);
    }
#undef STAGE_A
#undef STAGE_B
#undef GL16
#undef LDSW

    // -------- LDS-staged coalesced epilogue, XOR col-block swizzle --------
    // ep layout: elem (row, col) stored at row*64 + (col ^ (((row>>2)&3)<<4)).
    // Write: 16 lanes x 4 rows per store now cover 64 distinct banks-pairs
    // (2-way same-word = free). Read XORs identically; 16B reads stay
    // contiguous (XOR touches bits 4-5 of the element index only).
    __syncthreads();   // all waves done reading the K-loop LDS tiles
    bf16* ep = (wid < 4) ? ((bf16*)sA + wid * 8192)
                         : ((bf16*)sB + (wid - 4) * 8192);  // 16 KiB/wave: [128][64]
    const int frow = hi4 * 4;
    const long rowBase = (long)bRow * 256 + wr;
    const int  colBase = bCol * 256 + wc;
#pragma unroll
    for (int ni = 0; ni < 4; ++ni) {
        const int col = colBase + ni * 16 + fr;
        const float bi = bias ? bias[coff + col] : 0.0f;
#pragma unroll
        for (int mi = 0; mi < 8; ++mi) {
#pragma unroll
            for (int j = 0; j < 4; ++j) {
                float v = acc[mi][ni][j] + bi;
                if (ACT == 1) {  // gelu, tanh approx (max abs err ~7e-4)
                    const float u = v * (0.7978845608f + 0.0356774081f * v * v);
                    const float tnh = 1.0f - 2.0f / (__expf(2.0f * u) + 1.0f);
                    v = 0.5f * v * (1.0f + tnh);
                }
                const int erow = mi * 16 + frow + j;
                const int ecol = (ni * 16 + fr) ^ (((erow >> 2) & 3) << 4);
                ep[erow * 64 + ecol] = __float2bfloat16(v);
            }
        }
    }
    asm volatile("s_waitcnt lgkmcnt(0)" ::: "memory");
    __builtin_amdgcn_sched_barrier(0);
    // stream out: 16 rounds x 8 rows, 16B/lane fully-coalesced
    const int lr8 = lane >> 3;          // 0..7 row-in-round
    const int lc  = (lane & 7) * 8;     // col element offset
#pragma unroll
    for (int q2 = 0; q2 < 16; ++q2) {
        const int lrow = q2 * 8 + lr8;
        const int rcol = lc ^ (((lrow >> 2) & 3) << 4);
        const s8v vv = *(const s8v*)(&ep[lrow * 64 + rcol]);
        *(s8v*)(&C[(rowBase + lrow) * (long)ldc + coff + colBase + lc]) = vv;
    }
}

// ---------------------------------------------------------------------------
// Barrier-free attention over 9-token sequences (R9, measured BW-bound-good).
// ---------------------------------------------------------------------------
__device__ __forceinline__ int cell9(int branch, int g, int p)
{
    if (branch == 0) return g * 9 + p;
    if (branch == 1) return p * 9 + g;
    return ((g / 3) * 3 + p / 3) * 9 + (g % 3) * 3 + (p % 3);
}

__global__ __launch_bounds__(256)
void attn9(const bf16* __restrict__ qkv, bf16* __restrict__ outg,
           long chunk_base)
{
    __shared__ __align__(16) bf16 sW[4 * 9 * 392];
    __shared__ float sP[4][2][84];
    const int tid  = threadIdx.x;
    const int lane = tid & 63;
    const int w    = tid >> 6;
    const int branch = blockIdx.y;
    const int bx = blockIdx.x;
    const int s = (bx & 7) * (2304 >> 3) + (bx >> 3);
    const int b = s / 9, g = s % 9;
    const long brOff = (long)branch * 1536;
    bf16* myW = sW + w * (9 * 392);

#pragma unroll
    for (int rr = 0; rr < 7; ++rr) {
        const int c = rr * 64 + lane;
        if (c < 432) {
            const int p   = c / 48;
            const int rem = c - p * 48;
            const int seg = rem >> 3;
            const int ch  = rem & 7;
            const int col = (seg >> 1) * 512 + ((w << 1) + (seg & 1)) * 64 + ch * 8;
            const long tok = b * 81 + cell9(branch, g, p);
            *(s8v*)(&myW[p * 392 + seg * 64 + ch * 8]) =
                *(const s8v*)(&qkv[tok * 4608 + brOff + col]);
        }
    }
    asm volatile("s_waitcnt lgkmcnt(0) vmcnt(0)" ::: "memory");
    __builtin_amdgcn_sched_barrier(0);

#pragma unroll
    for (int rr = 0; rr < 3; ++rr) {
        const int idx = rr * 64 + lane;
        if (idx < 162) {
            const int h2 = idx / 81;
            const int pr = idx - h2 * 81;
            const int i = pr / 9, j = pr - (pr / 9) * 9;
            const bf16* qp = &myW[i * 392 + h2 * 64];
            const bf16* kp = &myW[j * 392 + 128 + h2 * 64];
            float accd = 0.0f;
#pragma unroll
            for (int dc = 0; dc < 8; ++dc) {
                s8v qv = *(const s8v*)(qp + dc * 8);
                s8v kv = *(const s8v*)(kp + dc * 8);
#pragma unroll
                for (int e2 = 0; e2 < 8; ++e2)
                    accd += bfs2f(qv[e2]) * bfs2f(kv[e2]);
            }
            sP[w][h2][pr] = accd * 0.125f;
        }
    }
    asm volatile("s_waitcnt lgkmcnt(0)" ::: "memory");
    __builtin_amdgcn_sched_barrier(0);

    if (lane < 18) {
        const int h2 = lane / 9, i = lane - (lane / 9) * 9;
        float* row = &sP[w][h2][i * 9];
        float m = row[0];
#pragma unroll
        for (int j = 1; j < 9; ++j) m = fmaxf(m, row[j]);
        float sum = 0.f, e[9];
#pragma unroll
        for (int j = 0; j < 9; ++j) { e[j] = expf(row[j] - m); sum += e[j]; }
        const float inv = 1.0f / sum;
#pragma unroll
        for (int j = 0; j < 9; ++j) row[j] = e[j] * inv;
    }
    asm volatile("s_waitcnt lgkmcnt(0)" ::: "memory");
    __builtin_amdgcn_sched_barrier(0);

#pragma unroll
    for (int rr = 0; rr < 3; ++rr) {
        const int idx = rr * 64 + lane;
        if (idx < 144) {
            const int h2  = idx / 72;
            const int rem = idx - h2 * 72;
            const int i  = rem >> 3;
            const int c8 = (rem & 7) * 8;
            const float* prow = &sP[w][h2][i * 9];
            float accv[8];
#pragma unroll
            for (int q2 = 0; q2 < 8; ++q2) accv[q2] = 0.f;
#pragma unroll
            for (int j = 0; j < 9; ++j) {
                const float p = prow[j];
                const s8v vv = *(const s8v*)(&myW[j * 392 + 256 + h2 * 64 + c8]);
#pragma unroll
                for (int q2 = 0; q2 < 8; ++q2)
                    accv[q2] += p * bfs2f(vv[q2]);
            }
            s8v ov;
#pragma unroll
            for (int q2 = 0; q2 < 8; ++q2) ov[q2] = f2bfs(accv[q2]);
            const long tok = b * 81 + cell9(branch, g, i);
            const int ocol = ((w << 1) + h2) * 64 + c8;
            *(s8v*)(&outg[(chunk_base + tok) * 1536 + branch * 512 + ocol]) = ov;
        }
    }
}

// ---------------------------------------------------------------------------
// Residual + LayerNorm: out = LN(x + mixed) * gamma + beta, E=512. fp32 I/O.
// ---------------------------------------------------------------------------
__global__ __launch_bounds__(256)
void ln_res(const float* __restrict__ x, const bf16* __restrict__ mixed,
            const float* __restrict__ gamma, const float* __restrict__ beta,
            float* __restrict__ out)
{
    const int tid = threadIdx.x;
    const int lane = tid & 63;
    const long row = (long)blockIdx.x * 4 + (tid >> 6);
    const long base = row * 512 + lane * 8;
    const float4 x0 = *(const float4*)(&x[base]);
    const float4 x1 = *(const float4*)(&x[base + 4]);
    const s8v mv = *(const s8v*)(&mixed[base]);
    float y[8];
    y[0] = x0.x + bfs2f(mv[0]); y[1] = x0.y + bfs2f(mv[1]);
    y[2] = x0.z + bfs2f(mv[2]); y[3] = x0.w + bfs2f(mv[3]);
    y[4] = x1.x + bfs2f(mv[4]); y[5] = x1.y + bfs2f(mv[5]);
    y[6] = x1.z + bfs2f(mv[6]); y[7] = x1.w + bfs2f(mv[7]);
    float sum = 0.f, sq = 0.f;
#pragma unroll
    for (int j = 0; j < 8; ++j) { sum += y[j]; sq += y[j] * y[j]; }
#pragma unroll
    for (int o = 32; o > 0; o >>= 1) {
        sum += __shfl_xor(sum, o, 64);
        sq  += __shfl_xor(sq, o, 64);
    }
    const float mean = sum * (1.f / 512.f);
    const float inv = rsqrtf(sq * (1.f / 512.f) - mean * mean + 1e-5f);
    const float4 g0 = *(const float4*)(&gamma[lane * 8]);
    const float4 g1 = *(const float4*)(&gamma[lane * 8 + 4]);
    const float4 b0 = *(const float4*)(&beta[lane * 8]);
    const float4 b1 = *(const float4*)(&beta[lane * 8 + 4]);
    float4 o0, o1;
    o0.x = (y[0] - mean) * inv * g0.x + b0.x;
    o0.y = (y[1] - mean) * inv * g0.y + b0.y;
    o0.z = (y[2] - mean) * inv * g0.z + b0.z;
    o0.w = (y[3] - mean) * inv * g0.w + b0.w;
    o1.x = (y[4] - mean) * inv * g1.x + b1.x;
    o1.y = (y[5] - mean) * inv * g1.y + b1.y;
    o1.z = (y[6] - mean) * inv * g1.z + b1.z;
    o1.w = (y[7] - mean) * inv * g1.w + b1.w;
    *(float4*)(&out[base]) = o0;
    *(float4*)(&out[base + 4]) = o1;
}

// ---------------------------------------------------------------------------
extern "C" void kernel_launch(void* const* d_in, const int* in_sizes, int n_in,
                              void* d_out, int out_size, void* d_ws, size_t ws_size,
                              hipStream_t stream)
{
    (void)in_sizes; (void)n_in; (void)out_size; (void)ws_size;
    const float* x     = (const float*)d_in[0];
    const float* w1f   = (const float*)d_in[13];
    const float* b1f   = (const float*)d_in[14];
    const float* b2f   = (const float*)d_in[16];
    const float* gamma = (const float*)d_in[17];
    const float* beta  = (const float*)d_in[18];

    // ---- workspace layout (total ~543 MB; proven-safe < 594.5 MB) ----
    char* ws = (char*)d_ws;
    bf16* attnall   = (bf16*)(ws);                    // [82944x1536]
    bf16* mixed     = (bf16*)(ws);                    // reuses attnall
    char* R         = ws + 254803968LL;
    bf16* qkv3chunk = (bf16*)(R);                     // [20736x4608]
    bf16* xb        = (bf16*)(R + 191102976LL);       // [82944x512]
    bf16* h         = (bf16*)(R);                     // [82944x1024] reuses R
    char* wb        = ws + 530841600LL;
    long off = 0;
    bf16* wqkv3_b = (bf16*)(wb + off); off += 4718592;   // [4608 x 512]
    bf16* woT_b[3];
    for (int i = 0; i < 3; ++i) { woT_b[i] = (bf16*)(wb + off); off += 524288; }
    bf16* w1_b  = (bf16*)(wb + off); off += 3145728;
    bf16* w2_b  = (bf16*)(wb + off); off += 1048576;
    bf16* Wp    = (bf16*)(wb + off); off += 3145728;
    float* b1p  = (float*)(wb + off); off += 4096;
    float* bqkv3 = (float*)(wb + off); off += 18432;     // [4608] fp32

    const dim3 blk(256, 1, 1);
    const dim3 blk512(512, 1, 1);

    // conversions
    cvt_f32_bf16<<<dim3(41472), blk, 0, stream>>>(x, xb, 10616832L);
    for (int i = 0; i < 3; ++i) {
        cvt_f32_bf16<<<dim3(768), blk, 0, stream>>>(
            (const float*)d_in[1 + i * 4], wqkv3_b + (long)i * 786432, 196608L);
        cvt_t_f32_bf16<<<dim3(16, 16), blk, 0, stream>>>(
            (const float*)d_in[3 + i * 4], woT_b[i], 512, 512);
        hipMemcpyAsync(bqkv3 + i * 1536, d_in[2 + i * 4], 1536 * sizeof(float),
                       hipMemcpyDeviceToDevice, stream);
    }
    cvt_f32_bf16<<<dim3(1536), blk, 0, stream>>>(w1f, w1_b, 393216L);
    cvt_f32_bf16<<<dim3(512), blk, 0, stream>>>((const float*)d_in[15], w2_b, 131072L);

    // bias fold: b1p = b1 + sum_br w1_br @ bo_br
    fold_b1<<<dim3(4), blk, 0, stream>>>(w1f, (const float*)d_in[4],
                                         (const float*)d_in[8], (const float*)d_in[12],
                                         b1f, b1p);

    // Wp[:, br*512+k] = (w1_br @ wo_br)[:, k]   M=1024, N=512, K=512
    for (int br = 0; br < 3; ++br)
        gemm256<0><<<dim3(2, 4), blk512, 0, stream>>>(
            w1_b + br * 512, woT_b[br], nullptr, Wp, 512, 1536, 1536, br * 512);

    // attention phase: 4 chunks of 256 batches (20736 rows)
    const long ROWS_C = 20736;
    for (int c = 0; c < 4; ++c) {
        const bf16* xA = xb + c * ROWS_C * 512;
        // qkv3 = x_chunk @ wqkv3^T + bqkv3   [20736, 4608]
        gemm256<0><<<dim3(18, 81), blk512, 0, stream>>>(
            xA, wqkv3_b, bqkv3, qkv3chunk, 512, 512, 4608, 0);
        // attention, all 3 branches -> attnall
        attn9<<<dim3(2304, 3), blk, 0, stream>>>(qkv3chunk, attnall, c * ROWS_C);
    }
    // h = gelu(attnall @ Wp^T + b1p)  [82944, 1024]
    gemm256<1><<<dim3(4, 324), blk512, 0, stream>>>(attnall, Wp, b1p, h, 1536, 1536, 1024, 0);
    // mixed = h @ w2^T + b2  [82944, 512]
    gemm256<0><<<dim3(2, 324), blk512, 0, stream>>>(h, w2_b, b2f, mixed, 1024, 1024, 512, 0);
    // out = LayerNorm(x + mixed), fp32
    ln_res<<<dim3(20736), blk, 0, stream>>>(x, mixed, gamma, beta, (float*)d_out);
}